// Round 4
// baseline (348.868 us; speedup 1.0000x reference)
//
#include <hip/hip_runtime.h>
#include <hip/hip_bf16.h>

#define L 1024
#define D 128
#define NB 32
#define BQ 16

typedef __attribute__((ext_vector_type(8))) short short8;
typedef __attribute__((ext_vector_type(4))) short short4v;
typedef __attribute__((ext_vector_type(4))) float f32x4;

__device__ __forceinline__ unsigned short f2bf(float f) {
    union { float f; unsigned int u; } x; x.f = f;
    unsigned int r = x.u + 0x7FFF + ((x.u >> 16) & 1);
    return (unsigned short)(r >> 16);
}
__device__ __forceinline__ float bf2f(unsigned short u) {
    union { unsigned int u; float f; } x; x.u = ((unsigned int)u) << 16;
    return x.f;
}

// ---------------------------------------------------------------------------
// Prep kernel (one launch):
//   blocks [0, 2048):    K fp32 [B][L][D] -> Kb bf16 [B][L][D]  (coalesced)
//   blocks [2048, 6144): V fp32 [B][L][D] -> Vt bf16 [B][D][L]  (32x32 LDS transpose)
// ---------------------------------------------------------------------------
__global__ void prep_kernel(const float* __restrict__ K, const float* __restrict__ V,
                            unsigned short* __restrict__ Kb, unsigned short* __restrict__ Vt) {
    __shared__ unsigned short t[32][40];
    int id = blockIdx.x;
    int tid = threadIdx.x;
    if (id < 2048) {
        size_t base = (size_t)id * 2048 + (size_t)tid * 8;
        float4 a = *(const float4*)(K + base);
        float4 c = *(const float4*)(K + base + 4);
        short8 o;
        o[0] = (short)f2bf(a.x); o[1] = (short)f2bf(a.y);
        o[2] = (short)f2bf(a.z); o[3] = (short)f2bf(a.w);
        o[4] = (short)f2bf(c.x); o[5] = (short)f2bf(c.y);
        o[6] = (short)f2bf(c.z); o[7] = (short)f2bf(c.w);
        *(short8*)(Kb + base) = o;
        return;
    }
    id -= 2048;
    int b = id >> 7;
    int rest = id & 127;
    int kt = rest >> 2, dt = rest & 3;
    int k0 = kt * 32, d0 = dt * 32;

    int kl = tid >> 3, dl4 = (tid & 7) * 4;
    const float* src = V + (((size_t)b * L + (k0 + kl)) * D) + d0 + dl4;
    float4 v = *(const float4*)src;
    t[dl4 + 0][kl] = f2bf(v.x);
    t[dl4 + 1][kl] = f2bf(v.y);
    t[dl4 + 2][kl] = f2bf(v.z);
    t[dl4 + 3][kl] = f2bf(v.w);
    __syncthreads();

    int dl = tid >> 3, kl4 = (tid & 7) * 4;
    unsigned short* dst = Vt + (((size_t)b * D + (d0 + dl)) * L) + k0 + kl4;
    short4v o;
    o[0] = (short)t[dl][kl4 + 0];
    o[1] = (short)t[dl][kl4 + 1];
    o[2] = (short)t[dl][kl4 + 2];
    o[3] = (short)t[dl][kl4 + 3];
    *(short4v*)dst = o;
}

// ---------------------------------------------------------------------------
// Fused attention, round 4. Swapped QK^T (mfma(K,Q) -> S^T): each thread's
// P-values are row-local (q = lane&15, k = (wave+4i)*16 + lg*4 + r).
//
//   Phase B (fused): per column-tile, load this thread's float4 of kg
//     (nontemporal, zero reuse), 4 MFMAs, p = exp(S), and store
//     t = p * kg  packed bf16 in 32 regs. g dies inside its iteration, so
//     peak pressure ~85 regs (rounds 0-3: carrying P AND a kg burst live
//     got spilled). e = exp(-(P/z1)*kg) = exp(-t/z1): t is formable
//     before z1 is known.
//   Phase D: pure VALU -- e = exp(-t*iz1), z2, e -> S16. ZERO global loads.
//   Phase E: unchanged (e @ V from Vt, scale by 1/z2).
//
// amdgpu_waves_per_eu(4,4): pin the allocator's occupancy TARGET at
// 4 waves/EU (128 VGPR budget). launch_bounds alone only bounds occupancy
// from below; the backend kept targeting 8/EU (64 VGPR) and spilling
// (round 3: WRITE_SIZE 16->53 MB = scratch). LDS caps us at 4 WGs/CU
// regardless, so nothing is lost.
// ---------------------------------------------------------------------------
__global__ __launch_bounds__(256) __attribute__((amdgpu_waves_per_eu(4, 4)))
void attn_kernel(const float* __restrict__ Q, const unsigned short* __restrict__ Kb,
                 const float* __restrict__ scale_p, const float* __restrict__ kg,
                 const unsigned short* __restrict__ Vt, float* __restrict__ out) {
    __shared__ unsigned short S16[BQ * 1032];   // 16 x (1024+8) bf16: e
    __shared__ float zp1[4][BQ];                // per-wave partial z1
    __shared__ float zp2[4][BQ];                // per-wave partial z2

    const int tid = threadIdx.x;
    const int b  = blockIdx.x >> 6;
    const int q0 = (blockIdx.x & 63) * BQ;
    const float nsc = -scale_p[0];

    const int wave = tid >> 6, lane = tid & 63;
    const int lr = lane & 15;
    const int lg = lane >> 4;

    // ---- Q fragments (B-operand of the swapped MFMA) ------------------------
    short8 aq[4];
#pragma unroll
    for (int kb = 0; kb < 4; kb++) {
        const float* qp = Q + (((size_t)b * L) + q0 + lr) * D + kb * 32 + lg * 8;
        float4 v0 = *(const float4*)qp;
        float4 v1 = *(const float4*)(qp + 4);
        short8 o;
        o[0] = (short)f2bf(v0.x * nsc); o[1] = (short)f2bf(v0.y * nsc);
        o[2] = (short)f2bf(v0.z * nsc); o[3] = (short)f2bf(v0.w * nsc);
        o[4] = (short)f2bf(v1.x * nsc); o[5] = (short)f2bf(v1.y * nsc);
        o[6] = (short)f2bf(v1.z * nsc); o[7] = (short)f2bf(v1.w * nsc);
        aq[kb] = o;
    }

    // ---- Phase B: S^T = K @ Q^T; t = exp(S)*kg packed bf16 in registers ----
    // This thread's kg coords: row q0+lr, cols wave*16 + 64*i + lg*4 + r.
    const float* kgq = kg + (((size_t)b * L) + q0 + lr) * L + wave * 16 + lg * 4;
    unsigned int tP[32];                        // 64 t-values, bf16-pair packed
    float z1p = 0.f;
#pragma unroll
    for (int i = 0; i < 16; i++) {
        int ct = wave + i * 4;
        f32x4 g = __builtin_nontemporal_load((const f32x4*)(kgq + 64 * i));
        const unsigned short* kp = Kb + (((size_t)b * L) + ct * 16 + lr) * D + lg * 8;
        f32x4 acc = {0.f, 0.f, 0.f, 0.f};
#pragma unroll
        for (int kb = 0; kb < 4; kb++) {
            short8 kf = *(const short8*)(kp + kb * 32);
            acc = __builtin_amdgcn_mfma_f32_16x16x32_bf16(kf, aq[kb], acc, 0, 0, 0);
        }
        float p0 = __expf(acc[0]);              // no max pass: S ~ N(0,1)
        float p1 = __expf(acc[1]);
        float p2 = __expf(acc[2]);
        float p3 = __expf(acc[3]);
        z1p += (p0 + p1) + (p2 + p3);
        tP[i * 2]     = ((unsigned int)f2bf(p1 * g[1]) << 16) | f2bf(p0 * g[0]);
        tP[i * 2 + 1] = ((unsigned int)f2bf(p3 * g[3]) << 16) | f2bf(p2 * g[2]);
    }
    // reduce z1 across the 4 lanes sharing this q-row (bits 4,5 of lane id)
    z1p += __shfl_xor(z1p, 16, 64);
    z1p += __shfl_xor(z1p, 32, 64);
    if (lg == 0) zp1[wave][lr] = z1p;
    __syncthreads();

    // ---- Phase D: e = exp(-t/z1), pure VALU, no global loads ---------------
    const float iz1 = 1.0f / (zp1[0][lr] + zp1[1][lr] + zp1[2][lr] + zp1[3][lr]);
    float z2p = 0.f;
#pragma unroll
    for (int j = 0; j < 16; j++) {
        int ct = wave + j * 4;
        float t0 = bf2f((unsigned short)(tP[j * 2] & 0xFFFF));
        float t1 = bf2f((unsigned short)(tP[j * 2] >> 16));
        float t2 = bf2f((unsigned short)(tP[j * 2 + 1] & 0xFFFF));
        float t3 = bf2f((unsigned short)(tP[j * 2 + 1] >> 16));
        float e0 = __expf(-t0 * iz1);
        float e1 = __expf(-t1 * iz1);
        float e2 = __expf(-t2 * iz1);
        float e3 = __expf(-t3 * iz1);
        z2p += (e0 + e1) + (e2 + e3);
        short4v o; o[0] = (short)f2bf(e0); o[1] = (short)f2bf(e1);
        o[2] = (short)f2bf(e2); o[3] = (short)f2bf(e3);
        *(short4v*)&S16[lr * 1032 + ct * 16 + lg * 4] = o;
    }
    z2p += __shfl_xor(z2p, 16, 64);
    z2p += __shfl_xor(z2p, 32, 64);
    if (lg == 0) zp2[wave][lr] = z2p;
    __syncthreads();

    // ---- Phase E: out = (e @ V) * (1/z2) ------------------------------------
    const int dt0 = wave * 2;
    f32x4 acc0 = {0.f, 0.f, 0.f, 0.f}, acc1 = {0.f, 0.f, 0.f, 0.f};
    const unsigned short* vt0 = Vt + (((size_t)b * D) + dt0 * 16 + lr) * L + lg * 8;
    const unsigned short* vt1 = vt0 + (size_t)16 * L;
    const unsigned short* brow = &S16[lr * 1032 + lg * 8];
#pragma unroll 8
    for (int kb = 0; kb < 32; kb++) {
        short8 a  = *(const short8*)(brow + kb * 32);
        short8 b0 = *(const short8*)(vt0 + kb * 32);
        short8 b1 = *(const short8*)(vt1 + kb * 32);
        acc0 = __builtin_amdgcn_mfma_f32_16x16x32_bf16(a, b0, acc0, 0, 0, 0);
        acc1 = __builtin_amdgcn_mfma_f32_16x16x32_bf16(a, b1, acc1, 0, 0, 0);
    }
    float* orow = out + (((size_t)b * L) + q0) * D;
#pragma unroll
    for (int r = 0; r < 4; r++) {
        int rq = lg * 4 + r;
        float rs = 1.0f / (zp2[0][rq] + zp2[1][rq] + zp2[2][rq] + zp2[3][rq]);
        orow[(size_t)rq * D + dt0 * 16 + lr]       = acc0[r] * rs;
        orow[(size_t)rq * D + (dt0 + 1) * 16 + lr] = acc1[r] * rs;
    }
}

extern "C" void kernel_launch(void* const* d_in, const int* in_sizes, int n_in,
                              void* d_out, int out_size, void* d_ws, size_t ws_size,
                              hipStream_t stream) {
    const float* Q     = (const float*)d_in[0];
    const float* K     = (const float*)d_in[1];
    const float* V     = (const float*)d_in[2];
    const float* scale = (const float*)d_in[3];
    const float* kg    = (const float*)d_in[4];
    float* out = (float*)d_out;
    unsigned short* Vt = (unsigned short*)d_ws;                        // 8 MB
    unsigned short* Kb = (unsigned short*)d_ws + (size_t)NB * D * L;   // 8 MB

    prep_kernel<<<6144, 256, 0, stream>>>(K, V, Kb, Vt);
    attn_kernel<<<NB * (L / BQ), 256, 0, stream>>>(Q, Kb, scale, kg, Vt, out);
}

// Round 6
// 337.564 us; speedup vs baseline: 1.0335x; 1.0335x over previous
//
#include <hip/hip_runtime.h>
#include <hip/hip_bf16.h>

#define L 1024
#define D 128
#define NB 32
#define BQ 16

typedef __attribute__((ext_vector_type(8))) short short8;
typedef __attribute__((ext_vector_type(4))) short short4v;
typedef __attribute__((ext_vector_type(4))) float f32x4;

__device__ __forceinline__ unsigned short f2bf(float f) {
    union { float f; unsigned int u; } x; x.f = f;
    unsigned int r = x.u + 0x7FFF + ((x.u >> 16) & 1);
    return (unsigned short)(r >> 16);
}
__device__ __forceinline__ float bf2f(unsigned short u) {
    union { unsigned int u; float f; } x; x.u = ((unsigned int)u) << 16;
    return x.f;
}

// ---------------------------------------------------------------------------
// Prep kernel (one launch):
//   blocks [0, 2048):    K fp32 [B][L][D] -> Kb bf16 [B][L][D]  (coalesced)
//   blocks [2048, 6144): V fp32 [B][L][D] -> Vt bf16 [B][D][L]  (32x32 LDS transpose)
// ---------------------------------------------------------------------------
__global__ void prep_kernel(const float* __restrict__ K, const float* __restrict__ V,
                            unsigned short* __restrict__ Kb, unsigned short* __restrict__ Vt) {
    __shared__ unsigned short t[32][40];
    int id = blockIdx.x;
    int tid = threadIdx.x;
    if (id < 2048) {
        size_t base = (size_t)id * 2048 + (size_t)tid * 8;
        float4 a = *(const float4*)(K + base);
        float4 c = *(const float4*)(K + base + 4);
        short8 o;
        o[0] = (short)f2bf(a.x); o[1] = (short)f2bf(a.y);
        o[2] = (short)f2bf(a.z); o[3] = (short)f2bf(a.w);
        o[4] = (short)f2bf(c.x); o[5] = (short)f2bf(c.y);
        o[6] = (short)f2bf(c.z); o[7] = (short)f2bf(c.w);
        *(short8*)(Kb + base) = o;
        return;
    }
    id -= 2048;
    int b = id >> 7;
    int rest = id & 127;
    int kt = rest >> 2, dt = rest & 3;
    int k0 = kt * 32, d0 = dt * 32;

    int kl = tid >> 3, dl4 = (tid & 7) * 4;
    const float* src = V + (((size_t)b * L + (k0 + kl)) * D) + d0 + dl4;
    float4 v = *(const float4*)src;
    t[dl4 + 0][kl] = f2bf(v.x);
    t[dl4 + 1][kl] = f2bf(v.y);
    t[dl4 + 2][kl] = f2bf(v.z);
    t[dl4 + 3][kl] = f2bf(v.w);
    __syncthreads();

    int dl = tid >> 3, kl4 = (tid & 7) * 4;
    unsigned short* dst = Vt + (((size_t)b * D + (d0 + dl)) * L) + k0 + kl4;
    short4v o;
    o[0] = (short)t[dl][kl4 + 0];
    o[1] = (short)t[dl][kl4 + 1];
    o[2] = (short)t[dl][kl4 + 2];
    o[3] = (short)t[dl][kl4 + 3];
    *(short4v*)dst = o;
}

// ---------------------------------------------------------------------------
// Fused attention, round 5 (resubmit; previous run died to a container
// failure, not the kernel). Swapped QK^T (mfma(K,Q) -> S^T): each thread's
// P-values are row-local (q = lane&15, k = (wave+4i)*16 + lg*4 + r).
//
// Rounds 0-4 lesson: the backend allocates ~64 VGPRs for this kernel no
// matter what (launch_bounds / waves_per_eu attempts all came back 52-64,
// spilling 30-50 MB to scratch when the source wanted more). So: design
// FOR 64 VGPRs. t = exp(S)*kg goes straight to LDS (S16) in Phase B
// instead of a 32-register array. Peak live set ~50 regs -> no spill.
//   Phase B (fused): per column-tile: nontemporal kg float4 load, 4 MFMAs,
//     p = exp(S), t = p*kg packed bf16 -> ds_write_b64 into S16. The 16
//     independent unrolled iterations keep the whole 134 MB kg stream
//     hidden under MFMA+exp work. z1 in regs (2 shuffles).
//     (e = exp(-(P/z1)*kg) = exp(-t/z1): t formable before z1 is known.)
//   Phase D: ds_read_b64 t (same thread, ~5 cyc vs the ~200+ cyc scratch
//     reads it replaces), e = exp(-t*iz1), z2, e -> same LDS slots.
//     ZERO global loads.
//   Phase E: unchanged (e @ V from Vt, scale by 1/z2).
// ---------------------------------------------------------------------------
__global__ __launch_bounds__(256, 4)
void attn_kernel(const float* __restrict__ Q, const unsigned short* __restrict__ Kb,
                 const float* __restrict__ scale_p, const float* __restrict__ kg,
                 const unsigned short* __restrict__ Vt, float* __restrict__ out) {
    __shared__ unsigned short S16[BQ * 1032];   // 16 x (1024+8) bf16: t -> e
    __shared__ float zp1[4][BQ];                // per-wave partial z1
    __shared__ float zp2[4][BQ];                // per-wave partial z2

    const int tid = threadIdx.x;
    const int b  = blockIdx.x >> 6;
    const int q0 = (blockIdx.x & 63) * BQ;
    const float nsc = -scale_p[0];

    const int wave = tid >> 6, lane = tid & 63;
    const int lr = lane & 15;
    const int lg = lane >> 4;

    // ---- Q fragments (B-operand of the swapped MFMA) ------------------------
    short8 aq[4];
#pragma unroll
    for (int kb = 0; kb < 4; kb++) {
        const float* qp = Q + (((size_t)b * L) + q0 + lr) * D + kb * 32 + lg * 8;
        float4 v0 = *(const float4*)qp;
        float4 v1 = *(const float4*)(qp + 4);
        short8 o;
        o[0] = (short)f2bf(v0.x * nsc); o[1] = (short)f2bf(v0.y * nsc);
        o[2] = (short)f2bf(v0.z * nsc); o[3] = (short)f2bf(v0.w * nsc);
        o[4] = (short)f2bf(v1.x * nsc); o[5] = (short)f2bf(v1.y * nsc);
        o[6] = (short)f2bf(v1.z * nsc); o[7] = (short)f2bf(v1.w * nsc);
        aq[kb] = o;
    }

    // ---- Phase B: S^T = K @ Q^T; t = exp(S)*kg -> LDS; z1 in regs ----------
    // This thread's kg coords: row q0+lr, cols wave*16 + 64*i + lg*4 + r.
    const float* kgq = kg + (((size_t)b * L) + q0 + lr) * L + wave * 16 + lg * 4;
    float z1p = 0.f;
#pragma unroll
    for (int i = 0; i < 16; i++) {
        int ct = wave + i * 4;
        f32x4 g = __builtin_nontemporal_load((const f32x4*)(kgq + 64 * i));
        const unsigned short* kp = Kb + (((size_t)b * L) + ct * 16 + lr) * D + lg * 8;
        f32x4 acc = {0.f, 0.f, 0.f, 0.f};
#pragma unroll
        for (int kb = 0; kb < 4; kb++) {
            short8 kf = *(const short8*)(kp + kb * 32);
            acc = __builtin_amdgcn_mfma_f32_16x16x32_bf16(kf, aq[kb], acc, 0, 0, 0);
        }
        float p0 = __expf(acc[0]);              // no max pass: S ~ N(0,1)
        float p1 = __expf(acc[1]);
        float p2 = __expf(acc[2]);
        float p3 = __expf(acc[3]);
        z1p += (p0 + p1) + (p2 + p3);
        short4v o;
        o[0] = (short)f2bf(p0 * g[0]); o[1] = (short)f2bf(p1 * g[1]);
        o[2] = (short)f2bf(p2 * g[2]); o[3] = (short)f2bf(p3 * g[3]);
        *(short4v*)&S16[lr * 1032 + ct * 16 + lg * 4] = o;
    }
    // reduce z1 across the 4 lanes sharing this q-row (bits 4,5 of lane id)
    z1p += __shfl_xor(z1p, 16, 64);
    z1p += __shfl_xor(z1p, 32, 64);
    if (lg == 0) zp1[wave][lr] = z1p;
    __syncthreads();

    // ---- Phase D: e = exp(-t/z1); pure LDS+VALU, no global loads -----------
    const float iz1 = 1.0f / (zp1[0][lr] + zp1[1][lr] + zp1[2][lr] + zp1[3][lr]);
    float z2p = 0.f;
#pragma unroll
    for (int j = 0; j < 16; j++) {
        int ct = wave + j * 4;
        short4v* pp = (short4v*)&S16[lr * 1032 + ct * 16 + lg * 4];
        short4v v = *pp;
        float e0 = __expf(-bf2f((unsigned short)v[0]) * iz1);
        float e1 = __expf(-bf2f((unsigned short)v[1]) * iz1);
        float e2 = __expf(-bf2f((unsigned short)v[2]) * iz1);
        float e3 = __expf(-bf2f((unsigned short)v[3]) * iz1);
        z2p += (e0 + e1) + (e2 + e3);
        short4v o; o[0] = (short)f2bf(e0); o[1] = (short)f2bf(e1);
        o[2] = (short)f2bf(e2); o[3] = (short)f2bf(e3);
        *pp = o;
    }
    z2p += __shfl_xor(z2p, 16, 64);
    z2p += __shfl_xor(z2p, 32, 64);
    if (lg == 0) zp2[wave][lr] = z2p;
    __syncthreads();

    // ---- Phase E: out = (e @ V) * (1/z2) ------------------------------------
    const int dt0 = wave * 2;
    f32x4 acc0 = {0.f, 0.f, 0.f, 0.f}, acc1 = {0.f, 0.f, 0.f, 0.f};
    const unsigned short* vt0 = Vt + (((size_t)b * D) + dt0 * 16 + lr) * L + lg * 8;
    const unsigned short* vt1 = vt0 + (size_t)16 * L;
    const unsigned short* brow = &S16[lr * 1032 + lg * 8];
#pragma unroll 8
    for (int kb = 0; kb < 32; kb++) {
        short8 a  = *(const short8*)(brow + kb * 32);
        short8 b0 = *(const short8*)(vt0 + kb * 32);
        short8 b1 = *(const short8*)(vt1 + kb * 32);
        acc0 = __builtin_amdgcn_mfma_f32_16x16x32_bf16(a, b0, acc0, 0, 0, 0);
        acc1 = __builtin_amdgcn_mfma_f32_16x16x32_bf16(a, b1, acc1, 0, 0, 0);
    }
    float* orow = out + (((size_t)b * L) + q0) * D;
#pragma unroll
    for (int r = 0; r < 4; r++) {
        int rq = lg * 4 + r;
        float rs = 1.0f / (zp2[0][rq] + zp2[1][rq] + zp2[2][rq] + zp2[3][rq]);
        orow[(size_t)rq * D + dt0 * 16 + lr]       = acc0[r] * rs;
        orow[(size_t)rq * D + (dt0 + 1) * 16 + lr] = acc1[r] * rs;
    }
}

extern "C" void kernel_launch(void* const* d_in, const int* in_sizes, int n_in,
                              void* d_out, int out_size, void* d_ws, size_t ws_size,
                              hipStream_t stream) {
    const float* Q     = (const float*)d_in[0];
    const float* K     = (const float*)d_in[1];
    const float* V     = (const float*)d_in[2];
    const float* scale = (const float*)d_in[3];
    const float* kg    = (const float*)d_in[4];
    float* out = (float*)d_out;
    unsigned short* Vt = (unsigned short*)d_ws;                        // 8 MB
    unsigned short* Kb = (unsigned short*)d_ws + (size_t)NB * D * L;   // 8 MB

    prep_kernel<<<6144, 256, 0, stream>>>(K, V, Kb, Vt);
    attn_kernel<<<NB * (L / BQ), 256, 0, stream>>>(Q, Kb, scale, kg, Vt, out);
}